// Round 15
// baseline (368.288 us; speedup 1.0000x reference)
//
#include <hip/hip_runtime.h>
#include <hip/hip_bf16.h>

// Problem constants
#define BB   2
#define LL   2048
#define DD   2048
#define HH   16
#define KVH  4
#define HDD  128
#define RDD  64
#define MM   (BB*LL)   // 4096 rows of x

typedef __attribute__((ext_vector_type(4))) float f32x4;
typedef __attribute__((ext_vector_type(8))) short bf16x8;
typedef unsigned short u16;

static __device__ __forceinline__ u16 f2b(float f) {
  __hip_bfloat16 b = __float2bfloat16(f);
  return *(const u16*)&b;
}

// async global(16B/lane) -> LDS (wave-uniform base + lane*16)
static __device__ __forceinline__ void gload_lds16(const void* g, void* l) {
  __builtin_amdgcn_global_load_lds(
      (const __attribute__((address_space(1))) unsigned int*)g,
      (__attribute__((address_space(3))) unsigned int*)l, 16, 0, 0);
}

// log2(e)/sqrt(128): scores land in exp2 domain
#define QSCALE 0.1275174313f

// ---------------- f32 -> bf16 cast (vectorized) ----------------
__global__ __launch_bounds__(256) void cast_bf16_kernel(const float* __restrict__ in,
                                                        u16* __restrict__ out, int n4) {
  int i = blockIdx.x * 256 + threadIdx.x;
  if (i >= n4) return;
  float4 v = ((const float4*)in)[i];
  ushort4 o;
  o.x = f2b(v.x); o.y = f2b(v.y); o.z = f2b(v.z); o.w = f2b(v.w);
  ((ushort4*)out)[i] = o;
}

// ---------------- small GEMM (N=64): C[M,N] = A @ W^T + bias ----------------
__global__ __launch_bounds__(64) void gemm_bf16_nt(const u16* __restrict__ A,
                                                   const u16* __restrict__ W,
                                                   const float* __restrict__ bias,
                                                   float* __restrict__ C,
                                                   int M, int N, int K) {
  const int n0 = blockIdx.x * 16;
  const int m0 = blockIdx.y * 16;
  const int lane = threadIdx.x;
  const int r  = lane & 15;
  const int kq = (lane >> 4) * 8;
  const u16* ap = A + (size_t)(m0 + r) * K + kq;
  const u16* wp = W + (size_t)(n0 + r) * K + kq;
  f32x4 acc = {0.f, 0.f, 0.f, 0.f};
  for (int k = 0; k < K; k += 32) {
    bf16x8 a = *(const bf16x8*)(ap + k);
    bf16x8 b = *(const bf16x8*)(wp + k);
    acc = __builtin_amdgcn_mfma_f32_16x16x32_bf16(a, b, acc, 0, 0, 0);
  }
  const int col = lane & 15;
  const int rg  = (lane >> 4) * 4;
  const float bv = bias[n0 + col];
#pragma unroll
  for (int i = 0; i < 4; ++i)
    C[(size_t)(m0 + rg + i) * N + (n0 + col)] = acc[i] + bv;
}

// ---------------- m97-style 128x128 tile GEMM (f32 out, for Wo) ----------------
__global__ __launch_bounds__(256) void gemm128(const u16* __restrict__ A,
                                               const u16* __restrict__ W,
                                               const float* __restrict__ bias,
                                               float* __restrict__ C,
                                               int M, int N, int K) {
  __shared__ u16 As[128 * 32];
  __shared__ u16 Bs[128 * 32];
  const int w = threadIdx.x >> 6, lane = threadIdx.x & 63;
  const int r = lane & 15, hi = lane >> 4, rg = hi * 4;
  const int wm = w >> 1, wn = w & 1;
  const int m0 = blockIdx.y * 128, n0 = blockIdx.x * 128;
  const int srow = w * 32 + (lane >> 2);
  const int scb  = (lane & 3) * 16;
  f32x4 acc[4][4];
#pragma unroll
  for (int i = 0; i < 4; ++i)
#pragma unroll
    for (int j = 0; j < 4; ++j) acc[i][j] = (f32x4){0.f, 0.f, 0.f, 0.f};

  for (int k0 = 0; k0 < K; k0 += 32) {
#pragma unroll
    for (int i = 0; i < 2; ++i) {
      gload_lds16((const char*)(A + (size_t)(m0 + srow + i * 16) * K + k0) + scb,
                  (char*)As + (w * 2 + i) * 1024);
      gload_lds16((const char*)(W + (size_t)(n0 + srow + i * 16) * K + k0) + scb,
                  (char*)Bs + (w * 2 + i) * 1024);
    }
    __syncthreads();
    bf16x8 a[4], b[4];
#pragma unroll
    for (int i = 0; i < 4; ++i)
      a[i] = *(const bf16x8*)((const char*)As + (wm * 64 + i * 16 + r) * 64 + hi * 16);
#pragma unroll
    for (int j = 0; j < 4; ++j)
      b[j] = *(const bf16x8*)((const char*)Bs + (wn * 64 + j * 16 + r) * 64 + hi * 16);
#pragma unroll
    for (int i = 0; i < 4; ++i)
#pragma unroll
      for (int j = 0; j < 4; ++j)
        acc[i][j] = __builtin_amdgcn_mfma_f32_16x16x32_bf16(a[i], b[j], acc[i][j], 0, 0, 0);
    __syncthreads();
  }
#pragma unroll
  for (int j = 0; j < 4; ++j) {
    const float bv = bias[n0 + wn * 64 + j * 16 + r];
#pragma unroll
    for (int i = 0; i < 4; ++i)
#pragma unroll
      for (int ii = 0; ii < 4; ++ii)
        C[(size_t)(m0 + wm * 64 + i * 16 + rg + ii) * N + n0 + wn * 64 + j * 16 + r] =
            acc[i][j][ii] + bv;
  }
}

// ---------------- fused Q GEMM: q = x@Wq^T + bq, rope+scale, bf16 granule images ----
// Q image: per 16-q tile 4KB: off_u16 = qt*2048 + (d>>5)*512 + ((d>>3)&3)*128 + (l&15)*8 + (d&7)
__global__ __launch_bounds__(256) void gemm_q_fused(const u16* __restrict__ A,
                                                    const u16* __restrict__ W,
                                                    const float* __restrict__ bias,
                                                    const float* __restrict__ cosb,
                                                    const float* __restrict__ sinb,
                                                    u16* __restrict__ Qb) {
  __shared__ u16 As[128 * 32];
  __shared__ u16 Bs[128 * 32];
  const int w = threadIdx.x >> 6, lane = threadIdx.x & 63;
  const int r = lane & 15, hi = lane >> 4, rg = hi * 4;
  const int wm = w >> 1, wn = w & 1;
  const int h = blockIdx.x;
  const int m0 = blockIdx.y * 128, n0 = h * 128;
  const int srow = w * 32 + (lane >> 2);
  const int scb  = (lane & 3) * 16;
  f32x4 acc[4][4];
#pragma unroll
  for (int i = 0; i < 4; ++i)
#pragma unroll
    for (int j = 0; j < 4; ++j) acc[i][j] = (f32x4){0.f, 0.f, 0.f, 0.f};

  for (int k0 = 0; k0 < DD; k0 += 32) {
#pragma unroll
    for (int i = 0; i < 2; ++i) {
      gload_lds16((const char*)(A + (size_t)(m0 + srow + i * 16) * DD + k0) + scb,
                  (char*)As + (w * 2 + i) * 1024);
      gload_lds16((const char*)(W + (size_t)(n0 + srow + i * 16) * DD + k0) + scb,
                  (char*)Bs + (w * 2 + i) * 1024);
    }
    __syncthreads();
    bf16x8 a[4], b[4];
#pragma unroll
    for (int i = 0; i < 4; ++i)
      a[i] = *(const bf16x8*)((const char*)As + (wm * 64 + i * 16 + r) * 64 + hi * 16);
#pragma unroll
    for (int j = 0; j < 4; ++j)
      b[j] = *(const bf16x8*)((const char*)Bs + (wn * 64 + j * 16 + r) * 64 + hi * 16);
#pragma unroll
    for (int i = 0; i < 4; ++i)
#pragma unroll
      for (int j = 0; j < 4; ++j)
        acc[i][j] = __builtin_amdgcn_mfma_f32_16x16x32_bf16(a[i], b[j], acc[i][j], 0, 0, 0);
    __syncthreads();
  }

  const int b = m0 >> 11;
  const int lbase = (m0 & 2047) + wm * 64;
  u16* Qimg = Qb + (size_t)((b * 16 + h) * 128) * 2048;
  if (wn == 0) {
#pragma unroll
    for (int j = 0; j < 4; ++j) {
      const int d = j * 16 + r;                     // < 64: no rope
      const float bv = bias[h * 128 + d];
#pragma unroll
      for (int i = 0; i < 4; ++i)
#pragma unroll
        for (int ii = 0; ii < 4; ++ii) {
          const int l = lbase + i * 16 + rg + ii;
          Qimg[(size_t)(l >> 4) * 2048 + (d >> 5) * 512 + ((d >> 3) & 3) * 128 +
               (l & 15) * 8 + (d & 7)] = f2b((acc[i][j][ii] + bv) * QSCALE);
        }
    }
  } else {
#pragma unroll
    for (int jp = 0; jp < 2; ++jp) {
      const int dd0 = jp * 16 + r;                  // 0..31
      const int dd1 = dd0 + 32;                     // 32..63
      const float bv0 = bias[h * 128 + 64 + dd0];
      const float bv1 = bias[h * 128 + 64 + dd1];
#pragma unroll
      for (int i = 0; i < 4; ++i)
#pragma unroll
        for (int ii = 0; ii < 4; ++ii) {
          const int l = lbase + i * 16 + rg + ii;
          const size_t nb = (size_t)(b * 2048 + l) * 64;
          const float c0 = cosb[nb + dd0], s0 = sinb[nb + dd0];
          const float c1 = cosb[nb + dd1], s1 = sinb[nb + dd1];
          const float a0 = acc[i][jp][ii] + bv0;
          const float a1 = acc[i][jp + 2][ii] + bv1;
          const float v0 = (a0 * c0 - a1 * s0) * QSCALE;
          const float v1 = (a1 * c1 + a0 * s1) * QSCALE;
          const int d0f = 64 + dd0, d1f = 64 + dd1;
          const size_t rowoff = (size_t)(l >> 4) * 2048 + (l & 15) * 8;
          Qimg[rowoff + (d0f >> 5) * 512 + ((d0f >> 3) & 3) * 128 + (d0f & 7)] = f2b(v0);
          Qimg[rowoff + (d1f >> 5) * 512 + ((d1f >> 3) & 3) * 128 + (d1f & 7)] = f2b(v1);
        }
    }
  }
}

// ---------------- fused KV GEMM -> 32-key-tile K-tied + interleaved-V images ----------------
// K image per 32-key tile 8KB: off = til*4096 + tt*2048 + ks*512 + hi*128 + r*8 (+d&7)
// V image per 32-key tile 8KB: off = til*4096 + (d>>4)*512 + ((lt>>2)&3)*128 + (d&15)*8
//                                     + ((lt>>4)&1)*4 + (lt&3)   [interleaved keys]
__global__ __launch_bounds__(256) void gemm_kv_fused(const u16* __restrict__ A,
                                                     const u16* __restrict__ W,
                                                     const float* __restrict__ bias,
                                                     u16* __restrict__ Kb,
                                                     u16* __restrict__ VTb) {
  __shared__ u16 As[128 * 32];
  __shared__ u16 Bs[128 * 32];
  const int w = threadIdx.x >> 6, lane = threadIdx.x & 63;
  const int r = lane & 15, hi = lane >> 4, rg = hi * 4;
  const int wm = w >> 1, wn = w & 1;
  const int c = blockIdx.x;
  const int m0 = blockIdx.y * 128, n0 = c * 128;
  const int srow = w * 32 + (lane >> 2);
  const int scb  = (lane & 3) * 16;
  f32x4 acc[4][4];
#pragma unroll
  for (int i = 0; i < 4; ++i)
#pragma unroll
    for (int j = 0; j < 4; ++j) acc[i][j] = (f32x4){0.f, 0.f, 0.f, 0.f};

  for (int k0 = 0; k0 < DD; k0 += 32) {
#pragma unroll
    for (int i = 0; i < 2; ++i) {
      gload_lds16((const char*)(A + (size_t)(m0 + srow + i * 16) * DD + k0) + scb,
                  (char*)As + (w * 2 + i) * 1024);
      gload_lds16((const char*)(W + (size_t)(n0 + srow + i * 16) * DD + k0) + scb,
                  (char*)Bs + (w * 2 + i) * 1024);
    }
    __syncthreads();
    bf16x8 a[4], b[4];
#pragma unroll
    for (int i = 0; i < 4; ++i)
      a[i] = *(const bf16x8*)((const char*)As + (wm * 64 + i * 16 + r) * 64 + hi * 16);
#pragma unroll
    for (int j = 0; j < 4; ++j)
      b[j] = *(const bf16x8*)((const char*)Bs + (wn * 64 + j * 16 + r) * 64 + hi * 16);
#pragma unroll
    for (int i = 0; i < 4; ++i)
#pragma unroll
      for (int j = 0; j < 4; ++j)
        acc[i][j] = __builtin_amdgcn_mfma_f32_16x16x32_bf16(a[i], b[j], acc[i][j], 0, 0, 0);
    __syncthreads();
  }

  const int b = m0 >> 11;
  const int lbase = (m0 & 2047) + wm * 64;
  u16* Kimg = Kb + (size_t)(b * KVH + c) * 64 * 4096;
  u16* Vimg = VTb + (size_t)(b * KVH + c) * 64 * 4096;
#pragma unroll
  for (int j = 0; j < 4; ++j) {
    const int d = wn * 64 + j * 16 + r;             // 0..127
    const float bv = bias[c * 128 + d];
#pragma unroll
    for (int i = 0; i < 4; ++i)
#pragma unroll
      for (int ii = 0; ii < 4; ++ii) {
        const int l = lbase + i * 16 + rg + ii;     // key
        const u16 bf = f2b(acc[i][j][ii] + bv);
        const int lt = l & 31;
        Vimg[(size_t)(l >> 5) * 4096 + (d >> 4) * 512 + ((lt >> 2) & 3) * 128 +
             (d & 15) * 8 + ((lt >> 4) & 1) * 4 + (lt & 3)] = bf;
        if (wn == 0)
          Kimg[(size_t)(l >> 5) * 4096 + ((lt >> 4) & 1) * 2048 + (d >> 5) * 512 +
               ((d >> 3) & 3) * 128 + (lt & 15) * 8 + (d & 7)] = bf;
      }
  }
}

// ---------------- build_kr: fill rope half (d>=64) of 32-key K images ----------------
// tid bits: r(4) hi(2) ks2(1) tt(1) til(9); til = bc*64+stile. 131072 granules.
__global__ __launch_bounds__(256) void build_kr(const float* __restrict__ krbuf,
                                                const float* __restrict__ cosb,
                                                const float* __restrict__ sinb,
                                                u16* __restrict__ Kb) {
  const int tid = blockIdx.x * 256 + threadIdx.x;
  const int r   = tid & 15;
  const int hi  = (tid >> 4) & 3;
  const int ks2 = (tid >> 6) & 1;                   // ks = 2 + ks2
  const int tt  = (tid >> 7) & 1;
  const int til = tid >> 8;                         // 0..511
  const int stile = til & 63, bc = til >> 6;
  const int b = bc >> 2;
  const int s = stile * 32 + tt * 16 + r;
  const int n = b * LL + s;
  const int i0 = ks2 * 32 + hi * 8;                 // 0..56
  const float* kr = krbuf + (size_t)n * RDD;
  const float* cb = cosb + (size_t)n * RDD + i0;
  const float* sb = sinb + (size_t)n * RDD + i0;
  float v[8];
  if (ks2 == 0) {
#pragma unroll
    for (int j = 0; j < 8; ++j) v[j] = kr[i0 + j] * cb[j] - kr[i0 + j + 32] * sb[j];
  } else {
#pragma unroll
    for (int j = 0; j < 8; ++j) v[j] = kr[i0 + j] * cb[j] + kr[i0 + j - 32] * sb[j];
  }
  u16 o[8];
#pragma unroll
  for (int j = 0; j < 8; ++j) o[j] = f2b(v[j]);
  u16* dst = Kb + (size_t)til * 4096 + tt * 2048 + (2 + ks2) * 512 + hi * 128 + r * 8;
  *(ushort4*)dst = *(ushort4*)&o[0];
  *(ushort4*)(dst + 4) = *(ushort4*)&o[4];
}

// ---------------- stage one 32-key tile (K+V images, 8KB each) for a 4-wave group ----
static __device__ __forceinline__ void stage_g(const u16* Kt, const u16* Vt,
                                               char* GB, int buf, int wg, int lane) {
#pragma unroll
  for (int i = 0; i < 2; ++i) {
    const int j = wg * 2 + i;                       // slot 0..7
    gload_lds16(Kt + (size_t)j * 512 + lane * 8, (u16*)(GB + buf * 8192) + j * 512);
    gload_lds16(Vt + (size_t)j * 512 + lane * 8, (u16*)(GB + 16384 + buf * 8192) + j * 512);
  }
}

// ---------------- MFMA flash attention v11: split-K, KVB=32, 2 blocks/CU ----------------
// 256 blocks x 512 threads. Block s: strips qb=15-s then qb=s. Per strip: group A
// (waves 0-3) tiles [0,2qb+2), group B tiles [2qb+2,4qb+4), private 16KB dbufs.
// LDS 66KB -> 2 resident blocks/CU (4 waves/SIMD, mutually async).
__global__ __launch_bounds__(512, 4) void attn_mfma11(const u16* __restrict__ Qb,
                                                      const u16* __restrict__ Kb,
                                                      const u16* __restrict__ VTb,
                                                      u16* __restrict__ attn_bf) {
  const int id = blockIdx.x;
  const int g = id & 31;
  const int s = id >> 5;                            // 0..7
  const int bc = g & 7, hlow = g >> 3;              // id%8 == bc -> XCD clustering
  const int b = bc >> 2, c = bc & 3;
  const int h = c * 4 + hlow;
  const int bh = b * 16 + h;
  const int w = threadIdx.x >> 6, lane = threadIdx.x & 63;
  const int r = lane & 15, hi = lane >> 4, rg = hi * 4;
  const int grp = w >> 2, wg = w & 3;

  __shared__ __align__(16) char LB[67584];          // 2 x 32KB group dbufs + 2KB mlp
  char* GB = LB + grp * 32768;

  const u16* Ktg = Kb + (size_t)(b * KVH + c) * 64 * 4096;
  const u16* Vtg = VTb + (size_t)(b * KVH + c) * 64 * 4096;

  for (int ss = 0; ss < 2; ++ss) {
    const int qb = ss ? s : (15 - s);
    const int q0 = qb * 128 + wg * 32;              // this wave's 32 q rows
    const int half = 2 * qb + 2;                    // 32-key tiles per group
    const int tb = grp ? half : 0;                  // group's first tile

    bf16x8 qf[2][4];
#pragma unroll
    for (int qs = 0; qs < 2; ++qs) {
      const u16* qtb = Qb + (size_t)(bh * 128 + qb * 8 + wg * 2 + qs) * 2048;
#pragma unroll
      for (int ks = 0; ks < 4; ++ks)
        qf[qs][ks] = *(const bf16x8*)(qtb + ks * 512 + lane * 8);
    }

    float m_[2] = {-3.0e38f, -3.0e38f}, l_[2] = {0.f, 0.f};
    f32x4 o[2][8];
#pragma unroll
    for (int qs = 0; qs < 2; ++qs)
#pragma unroll
      for (int t = 0; t < 8; ++t) o[qs][t] = (f32x4){0.f, 0.f, 0.f, 0.f};

    stage_g(Ktg + (size_t)tb * 4096, Vtg + (size_t)tb * 4096, GB, 0, wg, lane);
    __syncthreads();
    int cur = 0;

    for (int t = 0; t < half; ++t) {
      if (t + 1 < half)
        stage_g(Ktg + (size_t)(tb + t + 1) * 4096, Vtg + (size_t)(tb + t + 1) * 4096,
                GB, cur ^ 1, wg, lane);
      const int s0 = (tb + t) * 32;

      if (s0 <= q0 + 31) {                          // wave-uniform skip (group B early q)
        const u16* Kl = (const u16*)(GB + cur * 8192);
        const u16* Vl = (const u16*)(GB + 16384 + cur * 8192);

        // ---- swapped QK^T: query col = r, key rows = tt*16 + rg + i ----
        f32x4 st[2][2];
#pragma unroll
        for (int qs = 0; qs < 2; ++qs)
#pragma unroll
          for (int tt = 0; tt < 2; ++tt) st[qs][tt] = (f32x4){0.f, 0.f, 0.f, 0.f};
        __builtin_amdgcn_s_setprio(1);
#pragma unroll
        for (int tt = 0; tt < 2; ++tt) {
          bf16x8 kf[4];
#pragma unroll
          for (int ks = 0; ks < 4; ++ks)
            kf[ks] = *(const bf16x8*)(Kl + tt * 2048 + ks * 512 + lane * 8);
#pragma unroll
          for (int qs = 0; qs < 2; ++qs)
#pragma unroll
            for (int ks = 0; ks < 4; ++ks)
              st[qs][tt] = __builtin_amdgcn_mfma_f32_16x16x32_bf16(kf[ks], qf[qs][ks], st[qs][tt], 0, 0, 0);
        }
        __builtin_amdgcn_s_setprio(0);

        // ---- causal mask ----
        if (s0 + 31 > q0) {
#pragma unroll
          for (int qs = 0; qs < 2; ++qs)
#pragma unroll
            for (int tt = 0; tt < 2; ++tt)
#pragma unroll
              for (int i = 0; i < 4; ++i)
                if (s0 + tt * 16 + rg + i > q0 + qs * 16 + r) st[qs][tt][i] = -3.0e38f;
        }

        // ---- in-lane max + 2 shuffles ----
        float vmax[2];
#pragma unroll
        for (int qs = 0; qs < 2; ++qs) {
          float v = st[qs][0][0];
#pragma unroll
          for (int tt = 0; tt < 2; ++tt)
#pragma unroll
            for (int i = 0; i < 4; ++i) v = fmaxf(v, st[qs][tt][i]);
          v = fmaxf(v, __shfl_xor(v, 16));
          v = fmaxf(v, __shfl_xor(v, 32));
          vmax[qs] = v;
        }
        // ---- defer-max rescale ----
        const float grow = fmaxf(vmax[0] - m_[0], vmax[1] - m_[1]);
        if (!__all(grow <= 11.54f)) {
#pragma unroll
          for (int qs = 0; qs < 2; ++qs) {
            const float mn = fmaxf(m_[qs], vmax[qs]);
            const float cf = exp2f(m_[qs] - mn);
            l_[qs] *= cf;
            m_[qs] = mn;
#pragma unroll
            for (int tt = 0; tt < 8; ++tt)
#pragma unroll
              for (int i = 0; i < 4; ++i) o[qs][tt][i] *= cf;
          }
        }
        // ---- exp2 (in place) + sum + in-lane P fragments ----
        bf16x8 pa[2];
#pragma unroll
        for (int qs = 0; qs < 2; ++qs) {
          float ps = 0.f;
#pragma unroll
          for (int tt = 0; tt < 2; ++tt)
#pragma unroll
            for (int i = 0; i < 4; ++i) {
              st[qs][tt][i] = exp2f(st[qs][tt][i] - m_[qs]);
              ps += st[qs][tt][i];
            }
          ps += __shfl_xor(ps, 16);
          ps += __shfl_xor(ps, 32);
          l_[qs] += ps;
          bf16x8 v;
#pragma unroll
          for (int jj = 0; jj < 8; ++jj)
            v[jj] = (short)f2b(st[qs][jj >> 2][jj & 3]);
          pa[qs] = v;
        }

        // ---- PV: O(32q x 128d) += P(32x32) @ V(32x128), keys interleaved in both ----
        __builtin_amdgcn_s_setprio(1);
#pragma unroll
        for (int dt = 0; dt < 8; ++dt) {
          bf16x8 vf = *(const bf16x8*)(Vl + dt * 512 + lane * 8);
#pragma unroll
          for (int qs = 0; qs < 2; ++qs)
            o[qs][dt] = __builtin_amdgcn_mfma_f32_16x16x32_bf16(pa[qs], vf, o[qs][dt], 0, 0, 0);
        }
        __builtin_amdgcn_s_setprio(0);
      }

      __syncthreads();
      cur ^= 1;
    }

    // ---- split-K combine (groups hold disjoint KV halves of the same strip) ----
    float2* mlp = (float2*)(LB + 65536);
    if (hi == 0) {
      mlp[(w * 2 + 0) * 16 + r] = make_float2(m_[0], l_[0]);
      mlp[(w * 2 + 1) * 16 + r] = make_float2(m_[1], l_[1]);
    }
    __syncthreads();
    float lC[2], asc[2];
#pragma unroll
    for (int qs = 0; qs < 2; ++qs) {
      const float2 p = mlp[((w ^ 4) * 2 + qs) * 16 + r];
      const float mn = fmaxf(m_[qs], p.x);
      const float a1 = exp2f(m_[qs] - mn);
      lC[qs] = l_[qs] * a1 + p.y * exp2f(p.x - mn);
      asc[qs] = a1;
    }
#pragma unroll
    for (int qs = 0; qs < 2; ++qs) {
      float ai[4];
#pragma unroll
      for (int i = 0; i < 4; ++i) ai[i] = __shfl(asc[qs], (lane & 48) + rg + i);
#pragma unroll
      for (int tt = 0; tt < 8; ++tt)
#pragma unroll
        for (int i = 0; i < 4; ++i) o[qs][tt][i] *= ai[i];
    }
    if (grp == 1) {                                 // write rescaled partial O
#pragma unroll
      for (int qs = 0; qs < 2; ++qs)
#pragma unroll
        for (int tt = 0; tt < 8; ++tt)
          *(f32x4*)(LB + wg * 16384 + (qs * 8 + tt) * 1024 + lane * 16) = o[qs][tt];
    }
    __syncthreads();
    if (grp == 0) {                                 // merge + epilogue
#pragma unroll
      for (int qs = 0; qs < 2; ++qs) {
#pragma unroll
        for (int tt = 0; tt < 8; ++tt)
          o[qs][tt] += *(const f32x4*)(LB + wg * 16384 + (qs * 8 + tt) * 1024 + lane * 16);
        const float il = 1.f / lC[qs];
        float inv[4];
#pragma unroll
        for (int i = 0; i < 4; ++i) inv[i] = __shfl(il, (lane & 48) + rg + i);
        u16* op = attn_bf + (size_t)(b * LL + q0 + qs * 16 + rg) * DD + h * HDD;
#pragma unroll
        for (int tt = 0; tt < 8; ++tt)
#pragma unroll
          for (int i = 0; i < 4; ++i)
            op[(size_t)i * DD + tt * 16 + r] = f2b(o[qs][tt][i] * inv[i]);
      }
    }
    __syncthreads();
  }
}

extern "C" void kernel_launch(void* const* d_in, const int* in_sizes, int n_in,
                              void* d_out, int out_size, void* d_ws, size_t ws_size,
                              hipStream_t stream) {
  const float* x    = (const float*)d_in[0];
  const float* cosb = (const float*)d_in[1];
  const float* sinb = (const float*)d_in[2];
  const float* Wq   = (const float*)d_in[3];
  const float* bq   = (const float*)d_in[4];
  const float* Wkv  = (const float*)d_in[5];
  const float* bkv  = (const float*)d_in[6];
  const float* Wrk  = (const float*)d_in[7];
  const float* brk  = (const float*)d_in[8];
  const float* Wo   = (const float*)d_in[9];
  const float* bo   = (const float*)d_in[10];
  float* out = (float*)d_out;

  // Workspace layout (78,905,344 B total):
  char* ws = (char*)d_ws;
  u16*   Qb    = (u16*)(ws);                        // 16,777,216
  u16*   attn_bf = (u16*)(ws + 16777216);           // 16,777,216
  u16*   xb    = (u16*)(ws + 33554432);             // 16,777,216
  u16*   Wqb   = (u16*)(ws + 50331648);             //  8,388,608
  u16*   Wob   = (u16*)(ws + 58720256);             //  8,388,608
  u16*   Wkvb  = (u16*)(ws + 67108864);             //  2,097,152
  u16*   Wrkb  = (u16*)(ws + 69206016);             //    262,144
  float* krbuf = (float*)(ws + 69468160);           //  1,048,576
  u16*   Kb    = (u16*)(ws + 70516736);             //  4,194,304
  u16*   VTb   = (u16*)(ws + 74711040);             //  4,194,304 -> 78,905,344

  // 1) casts to bf16
  cast_bf16_kernel<<<(MM * DD / 4) / 256, 256, 0, stream>>>(x, xb, MM * DD / 4);
  cast_bf16_kernel<<<(HH * HDD * DD / 4) / 256, 256, 0, stream>>>(Wq, Wqb, HH * HDD * DD / 4);
  cast_bf16_kernel<<<(KVH * HDD * DD / 4) / 256, 256, 0, stream>>>(Wkv, Wkvb, KVH * HDD * DD / 4);
  cast_bf16_kernel<<<(RDD * DD / 4) / 256, 256, 0, stream>>>(Wrk, Wrkb, RDD * DD / 4);
  cast_bf16_kernel<<<(DD * HH * HDD / 4) / 256, 256, 0, stream>>>(Wo, Wob, DD * HH * HDD / 4);

  // 2) k_rope projection (f32, small)
  gemm_bf16_nt<<<dim3(RDD / 16, MM / 16), 64, 0, stream>>>(xb, Wrkb, brk, krbuf, MM, RDD, DD);

  // 3) fused projections -> attention operand images (no f32 intermediates)
  gemm_q_fused<<<dim3(HH, MM / 128), 256, 0, stream>>>(xb, Wqb, bq, cosb, sinb, Qb);
  gemm_kv_fused<<<dim3(KVH, MM / 128), 256, 0, stream>>>(xb, Wkvb, bkv, Kb, VTb);
  build_kr<<<512, 256, 0, stream>>>(krbuf, cosb, sinb, Kb);

  // 4) MFMA flash attention v11 -> bf16
  attn_mfma11<<<dim3(256), 512, 0, stream>>>(Qb, Kb, VTb, attn_bf);

  // 5) output projection -> d_out (f32)
  gemm128<<<dim3(DD / 128, MM / 128), 256, 0, stream>>>(attn_bf, Wob, bo, out, MM, DD, DD);
}

// Round 16
// 258.126 us; speedup vs baseline: 1.4268x; 1.4268x over previous
//
#include <hip/hip_runtime.h>
#include <hip/hip_bf16.h>

// Problem constants
#define BB   2
#define LL   2048
#define DD   2048
#define HH   16
#define KVH  4
#define HDD  128
#define RDD  64
#define MM   (BB*LL)   // 4096 rows of x

typedef __attribute__((ext_vector_type(4))) float f32x4;
typedef __attribute__((ext_vector_type(8))) short bf16x8;
typedef unsigned short u16;

static __device__ __forceinline__ u16 f2b(float f) {
  __hip_bfloat16 b = __float2bfloat16(f);
  return *(const u16*)&b;
}

// async global(16B/lane) -> LDS (wave-uniform base + lane*16)
static __device__ __forceinline__ void gload_lds16(const void* g, void* l) {
  __builtin_amdgcn_global_load_lds(
      (const __attribute__((address_space(1))) unsigned int*)g,
      (__attribute__((address_space(3))) unsigned int*)l, 16, 0, 0);
}

// log2(e)/sqrt(128): scores land in exp2 domain
#define QSCALE 0.1275174313f

// ---------------- f32 -> bf16 cast (vectorized) ----------------
__global__ __launch_bounds__(256) void cast_bf16_kernel(const float* __restrict__ in,
                                                        u16* __restrict__ out, int n4) {
  int i = blockIdx.x * 256 + threadIdx.x;
  if (i >= n4) return;
  float4 v = ((const float4*)in)[i];
  ushort4 o;
  o.x = f2b(v.x); o.y = f2b(v.y); o.z = f2b(v.z); o.w = f2b(v.w);
  ((ushort4*)out)[i] = o;
}

// ---------------- small GEMM (N=64): C[M,N] = A @ W^T + bias ----------------
__global__ __launch_bounds__(64) void gemm_bf16_nt(const u16* __restrict__ A,
                                                   const u16* __restrict__ W,
                                                   const float* __restrict__ bias,
                                                   float* __restrict__ C,
                                                   int M, int N, int K) {
  const int n0 = blockIdx.x * 16;
  const int m0 = blockIdx.y * 16;
  const int lane = threadIdx.x;
  const int r  = lane & 15;
  const int kq = (lane >> 4) * 8;
  const u16* ap = A + (size_t)(m0 + r) * K + kq;
  const u16* wp = W + (size_t)(n0 + r) * K + kq;
  f32x4 acc = {0.f, 0.f, 0.f, 0.f};
  for (int k = 0; k < K; k += 32) {
    bf16x8 a = *(const bf16x8*)(ap + k);
    bf16x8 b = *(const bf16x8*)(wp + k);
    acc = __builtin_amdgcn_mfma_f32_16x16x32_bf16(a, b, acc, 0, 0, 0);
  }
  const int col = lane & 15;
  const int rg  = (lane >> 4) * 4;
  const float bv = bias[n0 + col];
#pragma unroll
  for (int i = 0; i < 4; ++i)
    C[(size_t)(m0 + rg + i) * N + (n0 + col)] = acc[i] + bv;
}

// ---------------- m97-style 128x128 tile GEMM (f32 out, for Wo) ----------------
__global__ __launch_bounds__(256) void gemm128(const u16* __restrict__ A,
                                               const u16* __restrict__ W,
                                               const float* __restrict__ bias,
                                               float* __restrict__ C,
                                               int M, int N, int K) {
  __shared__ u16 As[128 * 32];
  __shared__ u16 Bs[128 * 32];
  const int w = threadIdx.x >> 6, lane = threadIdx.x & 63;
  const int r = lane & 15, hi = lane >> 4, rg = hi * 4;
  const int wm = w >> 1, wn = w & 1;
  const int m0 = blockIdx.y * 128, n0 = blockIdx.x * 128;
  const int srow = w * 32 + (lane >> 2);
  const int scb  = (lane & 3) * 16;
  f32x4 acc[4][4];
#pragma unroll
  for (int i = 0; i < 4; ++i)
#pragma unroll
    for (int j = 0; j < 4; ++j) acc[i][j] = (f32x4){0.f, 0.f, 0.f, 0.f};

  for (int k0 = 0; k0 < K; k0 += 32) {
#pragma unroll
    for (int i = 0; i < 2; ++i) {
      gload_lds16((const char*)(A + (size_t)(m0 + srow + i * 16) * K + k0) + scb,
                  (char*)As + (w * 2 + i) * 1024);
      gload_lds16((const char*)(W + (size_t)(n0 + srow + i * 16) * K + k0) + scb,
                  (char*)Bs + (w * 2 + i) * 1024);
    }
    __syncthreads();
    bf16x8 a[4], b[4];
#pragma unroll
    for (int i = 0; i < 4; ++i)
      a[i] = *(const bf16x8*)((const char*)As + (wm * 64 + i * 16 + r) * 64 + hi * 16);
#pragma unroll
    for (int j = 0; j < 4; ++j)
      b[j] = *(const bf16x8*)((const char*)Bs + (wn * 64 + j * 16 + r) * 64 + hi * 16);
#pragma unroll
    for (int i = 0; i < 4; ++i)
#pragma unroll
      for (int j = 0; j < 4; ++j)
        acc[i][j] = __builtin_amdgcn_mfma_f32_16x16x32_bf16(a[i], b[j], acc[i][j], 0, 0, 0);
    __syncthreads();
  }
#pragma unroll
  for (int j = 0; j < 4; ++j) {
    const float bv = bias[n0 + wn * 64 + j * 16 + r];
#pragma unroll
    for (int i = 0; i < 4; ++i)
#pragma unroll
      for (int ii = 0; ii < 4; ++ii)
        C[(size_t)(m0 + wm * 64 + i * 16 + rg + ii) * N + n0 + wn * 64 + j * 16 + r] =
            acc[i][j][ii] + bv;
  }
}

// ---------------- fused Q GEMM: q = x@Wq^T + bq, rope+scale, bf16 granule images ----
// Q image: per 16-q tile 4KB: off_u16 = qt*2048 + (d>>5)*512 + ((d>>3)&3)*128 + (l&15)*8 + (d&7)
__global__ __launch_bounds__(256) void gemm_q_fused(const u16* __restrict__ A,
                                                    const u16* __restrict__ W,
                                                    const float* __restrict__ bias,
                                                    const float* __restrict__ cosb,
                                                    const float* __restrict__ sinb,
                                                    u16* __restrict__ Qb) {
  __shared__ u16 As[128 * 32];
  __shared__ u16 Bs[128 * 32];
  const int w = threadIdx.x >> 6, lane = threadIdx.x & 63;
  const int r = lane & 15, hi = lane >> 4, rg = hi * 4;
  const int wm = w >> 1, wn = w & 1;
  const int h = blockIdx.x;
  const int m0 = blockIdx.y * 128, n0 = h * 128;
  const int srow = w * 32 + (lane >> 2);
  const int scb  = (lane & 3) * 16;
  f32x4 acc[4][4];
#pragma unroll
  for (int i = 0; i < 4; ++i)
#pragma unroll
    for (int j = 0; j < 4; ++j) acc[i][j] = (f32x4){0.f, 0.f, 0.f, 0.f};

  for (int k0 = 0; k0 < DD; k0 += 32) {
#pragma unroll
    for (int i = 0; i < 2; ++i) {
      gload_lds16((const char*)(A + (size_t)(m0 + srow + i * 16) * DD + k0) + scb,
                  (char*)As + (w * 2 + i) * 1024);
      gload_lds16((const char*)(W + (size_t)(n0 + srow + i * 16) * DD + k0) + scb,
                  (char*)Bs + (w * 2 + i) * 1024);
    }
    __syncthreads();
    bf16x8 a[4], b[4];
#pragma unroll
    for (int i = 0; i < 4; ++i)
      a[i] = *(const bf16x8*)((const char*)As + (wm * 64 + i * 16 + r) * 64 + hi * 16);
#pragma unroll
    for (int j = 0; j < 4; ++j)
      b[j] = *(const bf16x8*)((const char*)Bs + (wn * 64 + j * 16 + r) * 64 + hi * 16);
#pragma unroll
    for (int i = 0; i < 4; ++i)
#pragma unroll
      for (int j = 0; j < 4; ++j)
        acc[i][j] = __builtin_amdgcn_mfma_f32_16x16x32_bf16(a[i], b[j], acc[i][j], 0, 0, 0);
    __syncthreads();
  }

  const int b = m0 >> 11;
  const int lbase = (m0 & 2047) + wm * 64;
  u16* Qimg = Qb + (size_t)((b * 16 + h) * 128) * 2048;
  if (wn == 0) {
#pragma unroll
    for (int j = 0; j < 4; ++j) {
      const int d = j * 16 + r;                     // < 64: no rope
      const float bv = bias[h * 128 + d];
#pragma unroll
      for (int i = 0; i < 4; ++i)
#pragma unroll
        for (int ii = 0; ii < 4; ++ii) {
          const int l = lbase + i * 16 + rg + ii;
          Qimg[(size_t)(l >> 4) * 2048 + (d >> 5) * 512 + ((d >> 3) & 3) * 128 +
               (l & 15) * 8 + (d & 7)] = f2b((acc[i][j][ii] + bv) * QSCALE);
        }
    }
  } else {
#pragma unroll
    for (int jp = 0; jp < 2; ++jp) {
      const int dd0 = jp * 16 + r;                  // 0..31
      const int dd1 = dd0 + 32;                     // 32..63
      const float bv0 = bias[h * 128 + 64 + dd0];
      const float bv1 = bias[h * 128 + 64 + dd1];
#pragma unroll
      for (int i = 0; i < 4; ++i)
#pragma unroll
        for (int ii = 0; ii < 4; ++ii) {
          const int l = lbase + i * 16 + rg + ii;
          const size_t nb = (size_t)(b * 2048 + l) * 64;
          const float c0 = cosb[nb + dd0], s0 = sinb[nb + dd0];
          const float c1 = cosb[nb + dd1], s1 = sinb[nb + dd1];
          const float a0 = acc[i][jp][ii] + bv0;
          const float a1 = acc[i][jp + 2][ii] + bv1;
          const float v0 = (a0 * c0 - a1 * s0) * QSCALE;
          const float v1 = (a1 * c1 + a0 * s1) * QSCALE;
          const int d0f = 64 + dd0, d1f = 64 + dd1;
          const size_t rowoff = (size_t)(l >> 4) * 2048 + (l & 15) * 8;
          Qimg[rowoff + (d0f >> 5) * 512 + ((d0f >> 3) & 3) * 128 + (d0f & 7)] = f2b(v0);
          Qimg[rowoff + (d1f >> 5) * 512 + ((d1f >> 3) & 3) * 128 + (d1f & 7)] = f2b(v1);
        }
    }
  }
}

// ---------------- fused KV GEMM -> 32-key-tile K-tied + interleaved-V images ----------------
__global__ __launch_bounds__(256) void gemm_kv_fused(const u16* __restrict__ A,
                                                     const u16* __restrict__ W,
                                                     const float* __restrict__ bias,
                                                     u16* __restrict__ Kb,
                                                     u16* __restrict__ VTb) {
  __shared__ u16 As[128 * 32];
  __shared__ u16 Bs[128 * 32];
  const int w = threadIdx.x >> 6, lane = threadIdx.x & 63;
  const int r = lane & 15, hi = lane >> 4, rg = hi * 4;
  const int wm = w >> 1, wn = w & 1;
  const int c = blockIdx.x;
  const int m0 = blockIdx.y * 128, n0 = c * 128;
  const int srow = w * 32 + (lane >> 2);
  const int scb  = (lane & 3) * 16;
  f32x4 acc[4][4];
#pragma unroll
  for (int i = 0; i < 4; ++i)
#pragma unroll
    for (int j = 0; j < 4; ++j) acc[i][j] = (f32x4){0.f, 0.f, 0.f, 0.f};

  for (int k0 = 0; k0 < DD; k0 += 32) {
#pragma unroll
    for (int i = 0; i < 2; ++i) {
      gload_lds16((const char*)(A + (size_t)(m0 + srow + i * 16) * DD + k0) + scb,
                  (char*)As + (w * 2 + i) * 1024);
      gload_lds16((const char*)(W + (size_t)(n0 + srow + i * 16) * DD + k0) + scb,
                  (char*)Bs + (w * 2 + i) * 1024);
    }
    __syncthreads();
    bf16x8 a[4], b[4];
#pragma unroll
    for (int i = 0; i < 4; ++i)
      a[i] = *(const bf16x8*)((const char*)As + (wm * 64 + i * 16 + r) * 64 + hi * 16);
#pragma unroll
    for (int j = 0; j < 4; ++j)
      b[j] = *(const bf16x8*)((const char*)Bs + (wn * 64 + j * 16 + r) * 64 + hi * 16);
#pragma unroll
    for (int i = 0; i < 4; ++i)
#pragma unroll
      for (int j = 0; j < 4; ++j)
        acc[i][j] = __builtin_amdgcn_mfma_f32_16x16x32_bf16(a[i], b[j], acc[i][j], 0, 0, 0);
    __syncthreads();
  }

  const int b = m0 >> 11;
  const int lbase = (m0 & 2047) + wm * 64;
  u16* Kimg = Kb + (size_t)(b * KVH + c) * 64 * 4096;
  u16* Vimg = VTb + (size_t)(b * KVH + c) * 64 * 4096;
#pragma unroll
  for (int j = 0; j < 4; ++j) {
    const int d = wn * 64 + j * 16 + r;             // 0..127
    const float bv = bias[c * 128 + d];
#pragma unroll
    for (int i = 0; i < 4; ++i)
#pragma unroll
      for (int ii = 0; ii < 4; ++ii) {
        const int l = lbase + i * 16 + rg + ii;     // key
        const u16 bf = f2b(acc[i][j][ii] + bv);
        const int lt = l & 31;
        Vimg[(size_t)(l >> 5) * 4096 + (d >> 4) * 512 + ((lt >> 2) & 3) * 128 +
             (d & 15) * 8 + ((lt >> 4) & 1) * 4 + (lt & 3)] = bf;
        if (wn == 0)
          Kimg[(size_t)(l >> 5) * 4096 + ((lt >> 4) & 1) * 2048 + (d >> 5) * 512 +
               ((d >> 3) & 3) * 128 + (lt & 15) * 8 + (d & 7)] = bf;
      }
  }
}

// ---------------- build_kr: fill rope half (d>=64) of 32-key K images ----------------
__global__ __launch_bounds__(256) void build_kr(const float* __restrict__ krbuf,
                                                const float* __restrict__ cosb,
                                                const float* __restrict__ sinb,
                                                u16* __restrict__ Kb) {
  const int tid = blockIdx.x * 256 + threadIdx.x;
  const int r   = tid & 15;
  const int hi  = (tid >> 4) & 3;
  const int ks2 = (tid >> 6) & 1;                   // ks = 2 + ks2
  const int tt  = (tid >> 7) & 1;
  const int til = tid >> 8;                         // 0..511
  const int stile = til & 63, bc = til >> 6;
  const int b = bc >> 2;
  const int s = stile * 32 + tt * 16 + r;
  const int n = b * LL + s;
  const int i0 = ks2 * 32 + hi * 8;                 // 0..56
  const float* kr = krbuf + (size_t)n * RDD;
  const float* cb = cosb + (size_t)n * RDD + i0;
  const float* sb = sinb + (size_t)n * RDD + i0;
  float v[8];
  if (ks2 == 0) {
#pragma unroll
    for (int j = 0; j < 8; ++j) v[j] = kr[i0 + j] * cb[j] - kr[i0 + j + 32] * sb[j];
  } else {
#pragma unroll
    for (int j = 0; j < 8; ++j) v[j] = kr[i0 + j] * cb[j] + kr[i0 + j - 32] * sb[j];
  }
  u16 o[8];
#pragma unroll
  for (int j = 0; j < 8; ++j) o[j] = f2b(v[j]);
  u16* dst = Kb + (size_t)til * 4096 + tt * 2048 + (2 + ks2) * 512 + hi * 128 + r * 8;
  *(ushort4*)dst = *(ushort4*)&o[0];
  *(ushort4*)(dst + 4) = *(ushort4*)&o[4];
}

// ---------------- stage one 32-key tile (K+V images, 8KB each) for a 4-wave group ----
static __device__ __forceinline__ void stage_g(const u16* Kt, const u16* Vt,
                                               char* GB, int buf, int wg, int lane) {
#pragma unroll
  for (int i = 0; i < 2; ++i) {
    const int j = wg * 2 + i;                       // slot 0..7
    gload_lds16(Kt + (size_t)j * 512 + lane * 8, (u16*)(GB + buf * 8192) + j * 512);
    gload_lds16(Vt + (size_t)j * 512 + lane * 8, (u16*)(GB + 16384 + buf * 8192) + j * 512);
  }
}

// ---------------- MFMA flash attention v11b: split-K, KVB=32, 2 blocks/CU ----------------
// Identical to v11 except __launch_bounds__(512, 2): do NOT starve the register
// allocator (v11's (512,4) clamped VGPR to 64 -> accumulator spill, 153MB scratch
// writes). 96ish VGPR <= 128 still permits 4 waves/SIMD; LDS 66KB -> 2 blocks/CU.
__global__ __launch_bounds__(512, 2) void attn_mfma11(const u16* __restrict__ Qb,
                                                      const u16* __restrict__ Kb,
                                                      const u16* __restrict__ VTb,
                                                      u16* __restrict__ attn_bf) {
  const int id = blockIdx.x;
  const int g = id & 31;
  const int s = id >> 5;                            // 0..7
  const int bc = g & 7, hlow = g >> 3;              // id%8 == bc -> XCD clustering
  const int b = bc >> 2, c = bc & 3;
  const int h = c * 4 + hlow;
  const int bh = b * 16 + h;
  const int w = threadIdx.x >> 6, lane = threadIdx.x & 63;
  const int r = lane & 15, hi = lane >> 4, rg = hi * 4;
  const int grp = w >> 2, wg = w & 3;

  __shared__ __align__(16) char LB[67584];          // 2 x 32KB group dbufs + 2KB mlp
  char* GB = LB + grp * 32768;

  const u16* Ktg = Kb + (size_t)(b * KVH + c) * 64 * 4096;
  const u16* Vtg = VTb + (size_t)(b * KVH + c) * 64 * 4096;

  for (int ss = 0; ss < 2; ++ss) {
    const int qb = ss ? s : (15 - s);
    const int q0 = qb * 128 + wg * 32;              // this wave's 32 q rows
    const int half = 2 * qb + 2;                    // 32-key tiles per group
    const int tb = grp ? half : 0;                  // group's first tile

    bf16x8 qf[2][4];
#pragma unroll
    for (int qs = 0; qs < 2; ++qs) {
      const u16* qtb = Qb + (size_t)(bh * 128 + qb * 8 + wg * 2 + qs) * 2048;
#pragma unroll
      for (int ks = 0; ks < 4; ++ks)
        qf[qs][ks] = *(const bf16x8*)(qtb + ks * 512 + lane * 8);
    }

    float m_[2] = {-3.0e38f, -3.0e38f}, l_[2] = {0.f, 0.f};
    f32x4 o[2][8];
#pragma unroll
    for (int qs = 0; qs < 2; ++qs)
#pragma unroll
      for (int t = 0; t < 8; ++t) o[qs][t] = (f32x4){0.f, 0.f, 0.f, 0.f};

    stage_g(Ktg + (size_t)tb * 4096, Vtg + (size_t)tb * 4096, GB, 0, wg, lane);
    __syncthreads();
    int cur = 0;

    for (int t = 0; t < half; ++t) {
      if (t + 1 < half)
        stage_g(Ktg + (size_t)(tb + t + 1) * 4096, Vtg + (size_t)(tb + t + 1) * 4096,
                GB, cur ^ 1, wg, lane);
      const int s0 = (tb + t) * 32;

      if (s0 <= q0 + 31) {                          // wave-uniform skip (group B early q)
        const u16* Kl = (const u16*)(GB + cur * 8192);
        const u16* Vl = (const u16*)(GB + 16384 + cur * 8192);

        // ---- swapped QK^T: query col = r, key rows = tt*16 + rg + i ----
        f32x4 st[2][2];
#pragma unroll
        for (int qs = 0; qs < 2; ++qs)
#pragma unroll
          for (int tt = 0; tt < 2; ++tt) st[qs][tt] = (f32x4){0.f, 0.f, 0.f, 0.f};
        __builtin_amdgcn_s_setprio(1);
#pragma unroll
        for (int tt = 0; tt < 2; ++tt) {
          bf16x8 kf[4];
#pragma unroll
          for (int ks = 0; ks < 4; ++ks)
            kf[ks] = *(const bf16x8*)(Kl + tt * 2048 + ks * 512 + lane * 8);
#pragma unroll
          for (int qs = 0; qs < 2; ++qs)
#pragma unroll
            for (int ks = 0; ks < 4; ++ks)
              st[qs][tt] = __builtin_amdgcn_mfma_f32_16x16x32_bf16(kf[ks], qf[qs][ks], st[qs][tt], 0, 0, 0);
        }
        __builtin_amdgcn_s_setprio(0);

        // ---- causal mask ----
        if (s0 + 31 > q0) {
#pragma unroll
          for (int qs = 0; qs < 2; ++qs)
#pragma unroll
            for (int tt = 0; tt < 2; ++tt)
#pragma unroll
              for (int i = 0; i < 4; ++i)
                if (s0 + tt * 16 + rg + i > q0 + qs * 16 + r) st[qs][tt][i] = -3.0e38f;
        }

        // ---- in-lane max + 2 shuffles ----
        float vmax[2];
#pragma unroll
        for (int qs = 0; qs < 2; ++qs) {
          float v = st[qs][0][0];
#pragma unroll
          for (int tt = 0; tt < 2; ++tt)
#pragma unroll
            for (int i = 0; i < 4; ++i) v = fmaxf(v, st[qs][tt][i]);
          v = fmaxf(v, __shfl_xor(v, 16));
          v = fmaxf(v, __shfl_xor(v, 32));
          vmax[qs] = v;
        }
        // ---- defer-max rescale ----
        const float grow = fmaxf(vmax[0] - m_[0], vmax[1] - m_[1]);
        if (!__all(grow <= 11.54f)) {
#pragma unroll
          for (int qs = 0; qs < 2; ++qs) {
            const float mn = fmaxf(m_[qs], vmax[qs]);
            const float cf = exp2f(m_[qs] - mn);
            l_[qs] *= cf;
            m_[qs] = mn;
#pragma unroll
            for (int tt = 0; tt < 8; ++tt)
#pragma unroll
              for (int i = 0; i < 4; ++i) o[qs][tt][i] *= cf;
          }
        }
        // ---- exp2 (in place) + sum + in-lane P fragments ----
        bf16x8 pa[2];
#pragma unroll
        for (int qs = 0; qs < 2; ++qs) {
          float ps = 0.f;
#pragma unroll
          for (int tt = 0; tt < 2; ++tt)
#pragma unroll
            for (int i = 0; i < 4; ++i) {
              st[qs][tt][i] = exp2f(st[qs][tt][i] - m_[qs]);
              ps += st[qs][tt][i];
            }
          ps += __shfl_xor(ps, 16);
          ps += __shfl_xor(ps, 32);
          l_[qs] += ps;
          bf16x8 v;
#pragma unroll
          for (int jj = 0; jj < 8; ++jj)
            v[jj] = (short)f2b(st[qs][jj >> 2][jj & 3]);
          pa[qs] = v;
        }

        // ---- PV: O(32q x 128d) += P(32x32) @ V(32x128), keys interleaved in both ----
        __builtin_amdgcn_s_setprio(1);
#pragma unroll
        for (int dt = 0; dt < 8; ++dt) {
          bf16x8 vf = *(const bf16x8*)(Vl + dt * 512 + lane * 8);
#pragma unroll
          for (int qs = 0; qs < 2; ++qs)
            o[qs][dt] = __builtin_amdgcn_mfma_f32_16x16x32_bf16(pa[qs], vf, o[qs][dt], 0, 0, 0);
        }
        __builtin_amdgcn_s_setprio(0);
      }

      __syncthreads();
      cur ^= 1;
    }

    // ---- split-K combine (groups hold disjoint KV halves of the same strip) ----
    float2* mlp = (float2*)(LB + 65536);
    if (hi == 0) {
      mlp[(w * 2 + 0) * 16 + r] = make_float2(m_[0], l_[0]);
      mlp[(w * 2 + 1) * 16 + r] = make_float2(m_[1], l_[1]);
    }
    __syncthreads();
    float lC[2], asc[2];
#pragma unroll
    for (int qs = 0; qs < 2; ++qs) {
      const float2 p = mlp[((w ^ 4) * 2 + qs) * 16 + r];
      const float mn = fmaxf(m_[qs], p.x);
      const float a1 = exp2f(m_[qs] - mn);
      lC[qs] = l_[qs] * a1 + p.y * exp2f(p.x - mn);
      asc[qs] = a1;
    }
#pragma unroll
    for (int qs = 0; qs < 2; ++qs) {
      float ai[4];
#pragma unroll
      for (int i = 0; i < 4; ++i) ai[i] = __shfl(asc[qs], (lane & 48) + rg + i);
#pragma unroll
      for (int tt = 0; tt < 8; ++tt)
#pragma unroll
        for (int i = 0; i < 4; ++i) o[qs][tt][i] *= ai[i];
    }
    if (grp == 1) {                                 // write rescaled partial O
#pragma unroll
      for (int qs = 0; qs < 2; ++qs)
#pragma unroll
        for (int tt = 0; tt < 8; ++tt)
          *(f32x4*)(LB + wg * 16384 + (qs * 8 + tt) * 1024 + lane * 16) = o[qs][tt];
    }
    __syncthreads();
    if (grp == 0) {                                 // merge + epilogue
#pragma unroll
      for (int qs = 0; qs < 2; ++qs) {
#pragma unroll
        for (int tt = 0; tt < 8; ++tt)
          o[qs][tt] += *(const f32x4*)(LB + wg * 16384 + (qs * 8 + tt) * 1024 + lane * 16);
        const float il = 1.f / lC[qs];
        float inv[4];
#pragma unroll
        for (int i = 0; i < 4; ++i) inv[i] = __shfl(il, (lane & 48) + rg + i);
        u16* op = attn_bf + (size_t)(b * LL + q0 + qs * 16 + rg) * DD + h * HDD;
#pragma unroll
        for (int tt = 0; tt < 8; ++tt)
#pragma unroll
          for (int i = 0; i < 4; ++i)
            op[(size_t)i * DD + tt * 16 + r] = f2b(o[qs][tt][i] * inv[i]);
      }
    }
    __syncthreads();
  }
}

extern "C" void kernel_launch(void* const* d_in, const int* in_sizes, int n_in,
                              void* d_out, int out_size, void* d_ws, size_t ws_size,
                              hipStream_t stream) {
  const float* x    = (const float*)d_in[0];
  const float* cosb = (const float*)d_in[1];
  const float* sinb = (const float*)d_in[2];
  const float* Wq   = (const float*)d_in[3];
  const float* bq   = (const float*)d_in[4];
  const float* Wkv  = (const float*)d_in[5];
  const float* bkv  = (const float*)d_in[6];
  const float* Wrk  = (const float*)d_in[7];
  const float* brk  = (const float*)d_in[8];
  const float* Wo   = (const float*)d_in[9];
  const float* bo   = (const float*)d_in[10];
  float* out = (float*)d_out;

  // Workspace layout (78,905,344 B total):
  char* ws = (char*)d_ws;
  u16*   Qb    = (u16*)(ws);                        // 16,777,216
  u16*   attn_bf = (u16*)(ws + 16777216);           // 16,777,216
  u16*   xb    = (u16*)(ws + 33554432);             // 16,777,216
  u16*   Wqb   = (u16*)(ws + 50331648);             //  8,388,608
  u16*   Wob   = (u16*)(ws + 58720256);             //  8,388,608
  u16*   Wkvb  = (u16*)(ws + 67108864);             //  2,097,152
  u16*   Wrkb  = (u16*)(ws + 69206016);             //    262,144
  float* krbuf = (float*)(ws + 69468160);           //  1,048,576
  u16*   Kb    = (u16*)(ws + 70516736);             //  4,194,304
  u16*   VTb   = (u16*)(ws + 74711040);             //  4,194,304 -> 78,905,344

  // 1) casts to bf16
  cast_bf16_kernel<<<(MM * DD / 4) / 256, 256, 0, stream>>>(x, xb, MM * DD / 4);
  cast_bf16_kernel<<<(HH * HDD * DD / 4) / 256, 256, 0, stream>>>(Wq, Wqb, HH * HDD * DD / 4);
  cast_bf16_kernel<<<(KVH * HDD * DD / 4) / 256, 256, 0, stream>>>(Wkv, Wkvb, KVH * HDD * DD / 4);
  cast_bf16_kernel<<<(RDD * DD / 4) / 256, 256, 0, stream>>>(Wrk, Wrkb, RDD * DD / 4);
  cast_bf16_kernel<<<(DD * HH * HDD / 4) / 256, 256, 0, stream>>>(Wo, Wob, DD * HH * HDD / 4);

  // 2) k_rope projection (f32, small)
  gemm_bf16_nt<<<dim3(RDD / 16, MM / 16), 64, 0, stream>>>(xb, Wrkb, brk, krbuf, MM, RDD, DD);

  // 3) fused projections -> attention operand images (no f32 intermediates)
  gemm_q_fused<<<dim3(HH, MM / 128), 256, 0, stream>>>(xb, Wqb, bq, cosb, sinb, Qb);
  gemm_kv_fused<<<dim3(KVH, MM / 128), 256, 0, stream>>>(xb, Wkvb, bkv, Kb, VTb);
  build_kr<<<512, 256, 0, stream>>>(krbuf, cosb, sinb, Kb);

  // 4) MFMA flash attention v11b -> bf16
  attn_mfma11<<<dim3(256), 512, 0, stream>>>(Qb, Kb, VTb, attn_bf);

  // 5) output projection -> d_out (f32)
  gemm128<<<dim3(DD / 128, MM / 128), 256, 0, stream>>>(attn_bf, Wob, bo, out, MM, DD, DD);
}

// Round 18
// 231.540 us; speedup vs baseline: 1.5906x; 1.1148x over previous
//
#include <hip/hip_runtime.h>
#include <hip/hip_bf16.h>

// Problem constants
#define BB   2
#define LL   2048
#define DD   2048
#define HH   16
#define KVH  4
#define HDD  128
#define RDD  64
#define MM   (BB*LL)   // 4096 rows of x

typedef __attribute__((ext_vector_type(4))) float f32x4;
typedef __attribute__((ext_vector_type(8))) short bf16x8;
typedef unsigned short u16;

static __device__ __forceinline__ u16 f2b(float f) {
  __hip_bfloat16 b = __float2bfloat16(f);
  return *(const u16*)&b;
}

// async global(16B/lane) -> LDS (wave-uniform base + lane*16)
static __device__ __forceinline__ void gload_lds16(const void* g, void* l) {
  __builtin_amdgcn_global_load_lds(
      (const __attribute__((address_space(1))) unsigned int*)g,
      (__attribute__((address_space(3))) unsigned int*)l, 16, 0, 0);
}

// log2(e)/sqrt(128): scores land in exp2 domain
#define QSCALE 0.1275174313f

// ---------------- all f32->bf16 casts in ONE kernel (5 segments) ----------------
// float4 counts: x 2,097,152 | Wq 1,048,576 | Wkv 262,144 | Wrk 32,768 | Wo 1,048,576
// cumulative:      2,097,152 | 3,145,728    | 3,407,872   | 3,440,640  | 4,489,216
__global__ __launch_bounds__(256) void cast_all(const float* __restrict__ x,
                                                const float* __restrict__ Wq,
                                                const float* __restrict__ Wkv,
                                                const float* __restrict__ Wrk,
                                                const float* __restrict__ Wo,
                                                u16* __restrict__ xb, u16* __restrict__ Wqb,
                                                u16* __restrict__ Wkvb, u16* __restrict__ Wrkb,
                                                u16* __restrict__ Wob) {
  const int i = blockIdx.x * 256 + threadIdx.x;    // float4 index, total 4,489,216
  const float* src; u16* dst; int off;
  if (i < 2097152)      { src = x;   dst = xb;   off = i; }
  else if (i < 3145728) { src = Wq;  dst = Wqb;  off = i - 2097152; }
  else if (i < 3407872) { src = Wkv; dst = Wkvb; off = i - 3145728; }
  else if (i < 3440640) { src = Wrk; dst = Wrkb; off = i - 3407872; }
  else                  { src = Wo;  dst = Wob;  off = i - 3440640; }
  float4 v = ((const float4*)src)[off];
  ushort4 o;
  o.x = f2b(v.x); o.y = f2b(v.y); o.z = f2b(v.z); o.w = f2b(v.w);
  ((ushort4*)dst)[off] = o;
}

// ---------------- m97-style 128x128 tile GEMM (f32 out, for Wo) ----------------
__global__ __launch_bounds__(256) void gemm128(const u16* __restrict__ A,
                                               const u16* __restrict__ W,
                                               const float* __restrict__ bias,
                                               float* __restrict__ C,
                                               int M, int N, int K) {
  __shared__ u16 As[128 * 32];
  __shared__ u16 Bs[128 * 32];
  const int w = threadIdx.x >> 6, lane = threadIdx.x & 63;
  const int r = lane & 15, hi = lane >> 4, rg = hi * 4;
  const int wm = w >> 1, wn = w & 1;
  const int m0 = blockIdx.y * 128, n0 = blockIdx.x * 128;
  const int srow = w * 32 + (lane >> 2);
  const int scb  = (lane & 3) * 16;
  f32x4 acc[4][4];
#pragma unroll
  for (int i = 0; i < 4; ++i)
#pragma unroll
    for (int j = 0; j < 4; ++j) acc[i][j] = (f32x4){0.f, 0.f, 0.f, 0.f};

  for (int k0 = 0; k0 < K; k0 += 32) {
#pragma unroll
    for (int i = 0; i < 2; ++i) {
      gload_lds16((const char*)(A + (size_t)(m0 + srow + i * 16) * K + k0) + scb,
                  (char*)As + (w * 2 + i) * 1024);
      gload_lds16((const char*)(W + (size_t)(n0 + srow + i * 16) * K + k0) + scb,
                  (char*)Bs + (w * 2 + i) * 1024);
    }
    __syncthreads();
    bf16x8 a[4], b[4];
#pragma unroll
    for (int i = 0; i < 4; ++i)
      a[i] = *(const bf16x8*)((const char*)As + (wm * 64 + i * 16 + r) * 64 + hi * 16);
#pragma unroll
    for (int j = 0; j < 4; ++j)
      b[j] = *(const bf16x8*)((const char*)Bs + (wn * 64 + j * 16 + r) * 64 + hi * 16);
#pragma unroll
    for (int i = 0; i < 4; ++i)
#pragma unroll
      for (int j = 0; j < 4; ++j)
        acc[i][j] = __builtin_amdgcn_mfma_f32_16x16x32_bf16(a[i], b[j], acc[i][j], 0, 0, 0);
    __syncthreads();
  }
#pragma unroll
  for (int j = 0; j < 4; ++j) {
    const float bv = bias[n0 + wn * 64 + j * 16 + r];
#pragma unroll
    for (int i = 0; i < 4; ++i)
#pragma unroll
      for (int ii = 0; ii < 4; ++ii)
        C[(size_t)(m0 + wm * 64 + i * 16 + rg + ii) * N + n0 + wn * 64 + j * 16 + r] =
            acc[i][j][ii] + bv;
  }
}

// ---------------- fused Q GEMM: q = x@Wq^T + bq, rope+scale, bf16 granule images ----
// Q image: per 16-q tile 4KB: off_u16 = qt*2048 + (d>>5)*512 + ((d>>3)&3)*128 + (l&15)*8 + (d&7)
__global__ __launch_bounds__(256) void gemm_q_fused(const u16* __restrict__ A,
                                                    const u16* __restrict__ W,
                                                    const float* __restrict__ bias,
                                                    const float* __restrict__ cosb,
                                                    const float* __restrict__ sinb,
                                                    u16* __restrict__ Qb) {
  __shared__ u16 As[128 * 32];
  __shared__ u16 Bs[128 * 32];
  const int w = threadIdx.x >> 6, lane = threadIdx.x & 63;
  const int r = lane & 15, hi = lane >> 4, rg = hi * 4;
  const int wm = w >> 1, wn = w & 1;
  const int h = blockIdx.x;
  const int m0 = blockIdx.y * 128, n0 = h * 128;
  const int srow = w * 32 + (lane >> 2);
  const int scb  = (lane & 3) * 16;
  f32x4 acc[4][4];
#pragma unroll
  for (int i = 0; i < 4; ++i)
#pragma unroll
    for (int j = 0; j < 4; ++j) acc[i][j] = (f32x4){0.f, 0.f, 0.f, 0.f};

  for (int k0 = 0; k0 < DD; k0 += 32) {
#pragma unroll
    for (int i = 0; i < 2; ++i) {
      gload_lds16((const char*)(A + (size_t)(m0 + srow + i * 16) * DD + k0) + scb,
                  (char*)As + (w * 2 + i) * 1024);
      gload_lds16((const char*)(W + (size_t)(n0 + srow + i * 16) * DD + k0) + scb,
                  (char*)Bs + (w * 2 + i) * 1024);
    }
    __syncthreads();
    bf16x8 a[4], b[4];
#pragma unroll
    for (int i = 0; i < 4; ++i)
      a[i] = *(const bf16x8*)((const char*)As + (wm * 64 + i * 16 + r) * 64 + hi * 16);
#pragma unroll
    for (int j = 0; j < 4; ++j)
      b[j] = *(const bf16x8*)((const char*)Bs + (wn * 64 + j * 16 + r) * 64 + hi * 16);
#pragma unroll
    for (int i = 0; i < 4; ++i)
#pragma unroll
      for (int j = 0; j < 4; ++j)
        acc[i][j] = __builtin_amdgcn_mfma_f32_16x16x32_bf16(a[i], b[j], acc[i][j], 0, 0, 0);
    __syncthreads();
  }

  const int b = m0 >> 11;
  const int lbase = (m0 & 2047) + wm * 64;
  u16* Qimg = Qb + (size_t)((b * 16 + h) * 128) * 2048;
  if (wn == 0) {
#pragma unroll
    for (int j = 0; j < 4; ++j) {
      const int d = j * 16 + r;                     // < 64: no rope
      const float bv = bias[h * 128 + d];
#pragma unroll
      for (int i = 0; i < 4; ++i)
#pragma unroll
        for (int ii = 0; ii < 4; ++ii) {
          const int l = lbase + i * 16 + rg + ii;
          Qimg[(size_t)(l >> 4) * 2048 + (d >> 5) * 512 + ((d >> 3) & 3) * 128 +
               (l & 15) * 8 + (d & 7)] = f2b((acc[i][j][ii] + bv) * QSCALE);
        }
    }
  } else {
#pragma unroll
    for (int jp = 0; jp < 2; ++jp) {
      const int dd0 = jp * 16 + r;                  // 0..31
      const int dd1 = dd0 + 32;                     // 32..63
      const float bv0 = bias[h * 128 + 64 + dd0];
      const float bv1 = bias[h * 128 + 64 + dd1];
#pragma unroll
      for (int i = 0; i < 4; ++i)
#pragma unroll
        for (int ii = 0; ii < 4; ++ii) {
          const int l = lbase + i * 16 + rg + ii;
          const size_t nb = (size_t)(b * 2048 + l) * 64;
          const float c0 = cosb[nb + dd0], s0 = sinb[nb + dd0];
          const float c1 = cosb[nb + dd1], s1 = sinb[nb + dd1];
          const float a0 = acc[i][jp][ii] + bv0;
          const float a1 = acc[i][jp + 2][ii] + bv1;
          const float v0 = (a0 * c0 - a1 * s0) * QSCALE;
          const float v1 = (a1 * c1 + a0 * s1) * QSCALE;
          const int d0f = 64 + dd0, d1f = 64 + dd1;
          const size_t rowoff = (size_t)(l >> 4) * 2048 + (l & 15) * 8;
          Qimg[rowoff + (d0f >> 5) * 512 + ((d0f >> 3) & 3) * 128 + (d0f & 7)] = f2b(v0);
          Qimg[rowoff + (d1f >> 5) * 512 + ((d1f >> 3) & 3) * 128 + (d1f & 7)] = f2b(v1);
        }
    }
  }
}

// ---------------- fused KV GEMM -> 64-key-tile K-tied + interleaved-V images ----------------
__global__ __launch_bounds__(256) void gemm_kv_fused(const u16* __restrict__ A,
                                                     const u16* __restrict__ W,
                                                     const float* __restrict__ bias,
                                                     u16* __restrict__ Kb,
                                                     u16* __restrict__ VTb) {
  __shared__ u16 As[128 * 32];
  __shared__ u16 Bs[128 * 32];
  const int w = threadIdx.x >> 6, lane = threadIdx.x & 63;
  const int r = lane & 15, hi = lane >> 4, rg = hi * 4;
  const int wm = w >> 1, wn = w & 1;
  const int c = blockIdx.x;
  const int m0 = blockIdx.y * 128, n0 = c * 128;
  const int srow = w * 32 + (lane >> 2);
  const int scb  = (lane & 3) * 16;
  f32x4 acc[4][4];
#pragma unroll
  for (int i = 0; i < 4; ++i)
#pragma unroll
    for (int j = 0; j < 4; ++j) acc[i][j] = (f32x4){0.f, 0.f, 0.f, 0.f};

  for (int k0 = 0; k0 < DD; k0 += 32) {
#pragma unroll
    for (int i = 0; i < 2; ++i) {
      gload_lds16((const char*)(A + (size_t)(m0 + srow + i * 16) * DD + k0) + scb,
                  (char*)As + (w * 2 + i) * 1024);
      gload_lds16((const char*)(W + (size_t)(n0 + srow + i * 16) * DD + k0) + scb,
                  (char*)Bs + (w * 2 + i) * 1024);
    }
    __syncthreads();
    bf16x8 a[4], b[4];
#pragma unroll
    for (int i = 0; i < 4; ++i)
      a[i] = *(const bf16x8*)((const char*)As + (wm * 64 + i * 16 + r) * 64 + hi * 16);
#pragma unroll
    for (int j = 0; j < 4; ++j)
      b[j] = *(const bf16x8*)((const char*)Bs + (wn * 64 + j * 16 + r) * 64 + hi * 16);
#pragma unroll
    for (int i = 0; i < 4; ++i)
#pragma unroll
      for (int j = 0; j < 4; ++j)
        acc[i][j] = __builtin_amdgcn_mfma_f32_16x16x32_bf16(a[i], b[j], acc[i][j], 0, 0, 0);
    __syncthreads();
  }

  const int b = m0 >> 11;
  const int lbase = (m0 & 2047) + wm * 64;
  u16* Kimg = Kb + (size_t)(b * KVH + c) * 32 * 8192;
  u16* Vimg = VTb + (size_t)(b * KVH + c) * 32 * 8192;
#pragma unroll
  for (int j = 0; j < 4; ++j) {
    const int d = wn * 64 + j * 16 + r;             // 0..127
    const float bv = bias[c * 128 + d];
#pragma unroll
    for (int i = 0; i < 4; ++i)
#pragma unroll
      for (int ii = 0; ii < 4; ++ii) {
        const int l = lbase + i * 16 + rg + ii;     // key
        const u16 bf = f2b(acc[i][j][ii] + bv);
        const int lt = l & 63;
        Vimg[(size_t)(l >> 6) * 8192 + ((d >> 4) * 2 + ((lt >> 5) & 1)) * 512 +
             ((lt >> 2) & 3) * 128 + (d & 15) * 8 + ((lt >> 4) & 1) * 4 + (lt & 3)] = bf;
        if (wn == 0)
          Kimg[(size_t)(l >> 6) * 8192 + ((lt >> 4) & 3) * 2048 + (d >> 5) * 512 +
               ((d >> 3) & 3) * 128 + (lt & 15) * 8 + (d & 7)] = bf;
      }
  }
}

// ---------------- fused RK GEMM: k_rope = x@Wrk^T + brk, rope, -> K-image d>=64 ----
// grid (2, 256), 256 thr = 4 waves splitting K (512 each); LDS reduce; wave 0 epilogue.
__global__ __launch_bounds__(256) void gemm_rk_fused(const u16* __restrict__ A,
                                                     const u16* __restrict__ Wrkb,
                                                     const float* __restrict__ brk,
                                                     const float* __restrict__ cosb,
                                                     const float* __restrict__ sinb,
                                                     u16* __restrict__ Kb) {
  __shared__ f32x4 red[4][2][64];
  const int w = threadIdx.x >> 6, lane = threadIdx.x & 63;
  const int bx = blockIdx.x;                        // 0..1
  const int m0 = blockIdx.y * 16;
  const int r = lane & 15;
  const int kq = (lane >> 4) * 8;
  const u16* ap  = A + (size_t)(m0 + r) * DD + kq;
  const u16* wp0 = Wrkb + (size_t)(bx * 16 + r) * DD + kq;
  const u16* wp1 = Wrkb + (size_t)(bx * 16 + 32 + r) * DD + kq;
  f32x4 acc0 = {0.f, 0.f, 0.f, 0.f}, acc1 = {0.f, 0.f, 0.f, 0.f};
  for (int k = w * 512; k < w * 512 + 512; k += 32) {
    bf16x8 a  = *(const bf16x8*)(ap + k);
    bf16x8 b0 = *(const bf16x8*)(wp0 + k);
    bf16x8 b1 = *(const bf16x8*)(wp1 + k);
    acc0 = __builtin_amdgcn_mfma_f32_16x16x32_bf16(a, b0, acc0, 0, 0, 0);
    acc1 = __builtin_amdgcn_mfma_f32_16x16x32_bf16(a, b1, acc1, 0, 0, 0);
  }
  red[w][0][lane] = acc0;
  red[w][1][lane] = acc1;
  __syncthreads();
  if (w == 0) {
#pragma unroll
    for (int ww = 1; ww < 4; ++ww) {
      acc0 += red[ww][0][lane];
      acc1 += red[ww][1][lane];
    }
    const int rg = (lane >> 4) * 4;
    const int dd0 = bx * 16 + r, dd1 = dd0 + 32;
    const float bv0 = brk[dd0], bv1 = brk[dd1];
    const int d0f = 64 + dd0, d1f = 64 + dd1;
#pragma unroll
    for (int i = 0; i < 4; ++i) {
      const int n = m0 + rg + i;                    // global row
      const int b = n >> 11, l = n & 2047;
      const size_t nb = (size_t)n * 64;
      const float c0 = cosb[nb + dd0], s0 = sinb[nb + dd0];
      const float c1 = cosb[nb + dd1], s1 = sinb[nb + dd1];
      const float a0 = acc0[i] + bv0;
      const float a1 = acc1[i] + bv1;
      const u16 v0 = f2b(a0 * c0 - a1 * s0);        // K col 64+dd0
      const u16 v1 = f2b(a1 * c1 + a0 * s1);        // K col 64+dd1
      const int lt = l & 63;
      const size_t loff = (size_t)(l >> 6) * 8192 + ((lt >> 4) & 3) * 2048 + (lt & 15) * 8;
#pragma unroll
      for (int c = 0; c < 4; ++c) {
        u16* Kimg = Kb + (size_t)(b * KVH + c) * 32 * 8192;
        Kimg[loff + (d0f >> 5) * 512 + ((d0f >> 3) & 3) * 128 + (d0f & 7)] = v0;
        Kimg[loff + (d1f >> 5) * 512 + ((d1f >> 3) & 3) * 128 + (d1f & 7)] = v1;
      }
    }
  }
}

// ---------------- stage one 64-key tile for a 4-wave group ----------------
static __device__ __forceinline__ void stage_g(const u16* Kt, const u16* Vt,
                                               char* GB, int buf, int wg, int lane) {
#pragma unroll
  for (int i = 0; i < 4; ++i) {
    const int j = wg * 4 + i;                       // slot 0..15
    gload_lds16(Kt + (size_t)j * 512 + lane * 8, (u16*)(GB + buf * 16384) + j * 512);
    gload_lds16(Vt + (size_t)j * 512 + lane * 8, (u16*)(GB + 32768 + buf * 16384) + j * 512);
  }
}

// ---------------- MFMA flash attention v10: intra-block split-K, uniform blocks ----------------
__global__ __launch_bounds__(512, 2) void attn_mfma10(const u16* __restrict__ Qb,
                                                      const u16* __restrict__ Kb,
                                                      const u16* __restrict__ VTb,
                                                      u16* __restrict__ attn_bf) {
  const int id = blockIdx.x;
  const int g = id & 31;
  const int s = id >> 5;                            // 0..7
  const int bc = g & 7, hlow = g >> 3;              // id%8 == bc -> XCD clustering
  const int b = bc >> 2, c = bc & 3;
  const int h = c * 4 + hlow;
  const int bh = b * 16 + h;
  const int w = threadIdx.x >> 6, lane = threadIdx.x & 63;
  const int r = lane & 15, hi = lane >> 4, rg = hi * 4;
  const int grp = w >> 2, wg = w & 3;

  __shared__ __align__(16) char LB[131072];         // 2 groups x (K dbuf 32KB + V dbuf 32KB)
  char* GB = LB + grp * 65536;

  const u16* Ktg = Kb + (size_t)(b * KVH + c) * 32 * 8192;
  const u16* Vtg = VTb + (size_t)(b * KVH + c) * 32 * 8192;

  for (int ss = 0; ss < 2; ++ss) {
    const int qb = ss ? s : (15 - s);
    const int q0 = qb * 128 + wg * 32;              // this wave's 32 q rows
    const int half = qb + 1;                        // tiles per group (nt=2qb+2 even)
    const int tb = grp ? half : 0;                  // group's first tile

    bf16x8 qf[2][4];
#pragma unroll
    for (int qs = 0; qs < 2; ++qs) {
      const u16* qtb = Qb + (size_t)(bh * 128 + qb * 8 + wg * 2 + qs) * 2048;
#pragma unroll
      for (int ks = 0; ks < 4; ++ks)
        qf[qs][ks] = *(const bf16x8*)(qtb + ks * 512 + lane * 8);
    }

    float m_[2] = {-3.0e38f, -3.0e38f}, l_[2] = {0.f, 0.f};
    f32x4 o[2][8];
#pragma unroll
    for (int qs = 0; qs < 2; ++qs)
#pragma unroll
      for (int t = 0; t < 8; ++t) o[qs][t] = (f32x4){0.f, 0.f, 0.f, 0.f};

    stage_g(Ktg + (size_t)tb * 8192, Vtg + (size_t)tb * 8192, GB, 0, wg, lane);
    __syncthreads();
    int cur = 0;

    for (int t = 0; t < half; ++t) {
      if (t + 1 < half)
        stage_g(Ktg + (size_t)(tb + t + 1) * 8192, Vtg + (size_t)(tb + t + 1) * 8192,
                GB, cur ^ 1, wg, lane);
      const int s0 = (tb + t) * 64;

      if (s0 <= q0 + 31) {                          // wave-uniform skip (group B early q)
        const u16* Kl = (const u16*)(GB + cur * 16384);
        const u16* Vl = (const u16*)(GB + 32768 + cur * 16384);

        f32x4 st[2][4];
#pragma unroll
        for (int qs = 0; qs < 2; ++qs)
#pragma unroll
          for (int tt = 0; tt < 4; ++tt) st[qs][tt] = (f32x4){0.f, 0.f, 0.f, 0.f};
        __builtin_amdgcn_s_setprio(1);
#pragma unroll
        for (int tt = 0; tt < 4; ++tt) {
          bf16x8 kf[4];
#pragma unroll
          for (int ks = 0; ks < 4; ++ks)
            kf[ks] = *(const bf16x8*)(Kl + tt * 2048 + ks * 512 + lane * 8);
#pragma unroll
          for (int qs = 0; qs < 2; ++qs)
#pragma unroll
            for (int ks = 0; ks < 4; ++ks)
              st[qs][tt] = __builtin_amdgcn_mfma_f32_16x16x32_bf16(kf[ks], qf[qs][ks], st[qs][tt], 0, 0, 0);
        }
        __builtin_amdgcn_s_setprio(0);

        if (s0 + 63 > q0) {
#pragma unroll
          for (int qs = 0; qs < 2; ++qs)
#pragma unroll
            for (int tt = 0; tt < 4; ++tt)
#pragma unroll
              for (int i = 0; i < 4; ++i)
                if (s0 + tt * 16 + rg + i > q0 + qs * 16 + r) st[qs][tt][i] = -3.0e38f;
        }

        float vmax[2];
#pragma unroll
        for (int qs = 0; qs < 2; ++qs) {
          float v = st[qs][0][0];
#pragma unroll
          for (int tt = 0; tt < 4; ++tt)
#pragma unroll
            for (int i = 0; i < 4; ++i) v = fmaxf(v, st[qs][tt][i]);
          v = fmaxf(v, __shfl_xor(v, 16));
          v = fmaxf(v, __shfl_xor(v, 32));
          vmax[qs] = v;
        }
        const float grow = fmaxf(vmax[0] - m_[0], vmax[1] - m_[1]);
        if (!__all(grow <= 11.54f)) {
#pragma unroll
          for (int qs = 0; qs < 2; ++qs) {
            const float mn = fmaxf(m_[qs], vmax[qs]);
            const float cf = exp2f(m_[qs] - mn);
            l_[qs] *= cf;
            m_[qs] = mn;
#pragma unroll
            for (int tt = 0; tt < 8; ++tt)
#pragma unroll
              for (int i = 0; i < 4; ++i) o[qs][tt][i] *= cf;
          }
        }
        bf16x8 pa[2][2];
#pragma unroll
        for (int qs = 0; qs < 2; ++qs) {
          float ps = 0.f;
#pragma unroll
          for (int tt = 0; tt < 4; ++tt)
#pragma unroll
            for (int i = 0; i < 4; ++i) {
              st[qs][tt][i] = exp2f(st[qs][tt][i] - m_[qs]);
              ps += st[qs][tt][i];
            }
          ps += __shfl_xor(ps, 16);
          ps += __shfl_xor(ps, 32);
          l_[qs] += ps;
#pragma unroll
          for (int kb = 0; kb < 2; ++kb) {
            bf16x8 v;
#pragma unroll
            for (int jj = 0; jj < 8; ++jj)
              v[jj] = (short)f2b(st[qs][2 * kb + (jj >> 2)][jj & 3]);
            pa[qs][kb] = v;
          }
        }

        __builtin_amdgcn_s_setprio(1);
#pragma unroll
        for (int tt = 0; tt < 8; ++tt) {
#pragma unroll
          for (int kb = 0; kb < 2; ++kb) {
            bf16x8 vf = *(const bf16x8*)(Vl + tt * 1024 + kb * 512 + lane * 8);
#pragma unroll
            for (int qs = 0; qs < 2; ++qs)
              o[qs][tt] = __builtin_amdgcn_mfma_f32_16x16x32_bf16(pa[qs][kb], vf, o[qs][tt], 0, 0, 0);
          }
        }
        __builtin_amdgcn_s_setprio(0);
      }

      __syncthreads();
      cur ^= 1;
    }

    // ---- split-K combine ----
    float2* mlp = (float2*)(LB + 65536);
    if (hi == 0) {
      mlp[(w * 2 + 0) * 16 + r] = make_float2(m_[0], l_[0]);
      mlp[(w * 2 + 1) * 16 + r] = make_float2(m_[1], l_[1]);
    }
    __syncthreads();
    float lC[2], asc[2];
#pragma unroll
    for (int qs = 0; qs < 2; ++qs) {
      const float2 p = mlp[((w ^ 4) * 2 + qs) * 16 + r];
      const float mn = fmaxf(m_[qs], p.x);
      const float a1 = exp2f(m_[qs] - mn);
      lC[qs] = l_[qs] * a1 + p.y * exp2f(p.x - mn);
      asc[qs] = a1;
    }
#pragma unroll
    for (int qs = 0; qs < 2; ++qs) {
      float ai[4];
#pragma unroll
      for (int i = 0; i < 4; ++i) ai[i] = __shfl(asc[qs], (lane & 48) + rg + i);
#pragma unroll
      for (int tt = 0; tt < 8; ++tt)
#pragma unroll
        for (int i = 0; i < 4; ++i) o[qs][tt][i] *= ai[i];
    }
    if (grp == 1) {
#pragma unroll
      for (int qs = 0; qs < 2; ++qs)
#pragma unroll
        for (int tt = 0; tt < 8; ++tt)
          *(f32x4*)(LB + wg * 16384 + (qs * 8 + tt) * 1024 + lane * 16) = o[qs][tt];
    }
    __syncthreads();
    if (grp == 0) {
#pragma unroll
      for (int qs = 0; qs < 2; ++qs) {
#pragma unroll
        for (int tt = 0; tt < 8; ++tt)
          o[qs][tt] += *(const f32x4*)(LB + wg * 16384 + (qs * 8 + tt) * 1024 + lane * 16);
        const float il = 1.f / lC[qs];
        float inv[4];
#pragma unroll
        for (int i = 0; i < 4; ++i) inv[i] = __shfl(il, (lane & 48) + rg + i);
        u16* op = attn_bf + (size_t)(b * LL + q0 + qs * 16 + rg) * DD + h * HDD;
#pragma unroll
        for (int tt = 0; tt < 8; ++tt)
#pragma unroll
          for (int i = 0; i < 4; ++i)
            op[(size_t)i * DD + tt * 16 + r] = f2b(o[qs][tt][i] * inv[i]);
      }
    }
    __syncthreads();
  }
}

extern "C" void kernel_launch(void* const* d_in, const int* in_sizes, int n_in,
                              void* d_out, int out_size, void* d_ws, size_t ws_size,
                              hipStream_t stream) {
  const float* x    = (const float*)d_in[0];
  const float* cosb = (const float*)d_in[1];
  const float* sinb = (const float*)d_in[2];
  const float* Wq   = (const float*)d_in[3];
  const float* bq   = (const float*)d_in[4];
  const float* Wkv  = (const float*)d_in[5];
  const float* bkv  = (const float*)d_in[6];
  const float* Wrk  = (const float*)d_in[7];
  const float* brk  = (const float*)d_in[8];
  const float* Wo   = (const float*)d_in[9];
  const float* bo   = (const float*)d_in[10];
  float* out = (float*)d_out;

  // Workspace layout (78,905,344 B total):
  char* ws = (char*)d_ws;
  u16*   Qb    = (u16*)(ws);                        // 16,777,216
  u16*   attn_bf = (u16*)(ws + 16777216);           // 16,777,216
  u16*   xb    = (u16*)(ws + 33554432);             // 16,777,216
  u16*   Wqb   = (u16*)(ws + 50331648);             //  8,388,608
  u16*   Wob   = (u16*)(ws + 58720256);             //  8,388,608
  u16*   Wkvb  = (u16*)(ws + 67108864);             //  2,097,152
  u16*   Wrkb  = (u16*)(ws + 69206016);             //    262,144
  u16*   Kb    = (u16*)(ws + 70516736);             //  4,194,304
  u16*   VTb   = (u16*)(ws + 74711040);             //  4,194,304 -> 78,905,344

  // 1) all casts in one kernel (4,489,216 float4 / 256 = 17,536 blocks)
  cast_all<<<17536, 256, 0, stream>>>(x, Wq, Wkv, Wrk, Wo, xb, Wqb, Wkvb, Wrkb, Wob);

  // 2) fused projections -> attention operand images (no f32 intermediates)
  gemm_q_fused<<<dim3(HH, MM / 128), 256, 0, stream>>>(xb, Wqb, bq, cosb, sinb, Qb);
  gemm_kv_fused<<<dim3(KVH, MM / 128), 256, 0, stream>>>(xb, Wkvb, bkv, Kb, VTb);
  gemm_rk_fused<<<dim3(2, MM / 16), 256, 0, stream>>>(xb, Wrkb, brk, cosb, sinb, Kb);

  // 3) MFMA flash attention v10 -> bf16
  attn_mfma10<<<dim3(256), 512, 0, stream>>>(Qb, Kb, VTb, attn_bf);

  // 4) output projection -> d_out (f32)
  gemm128<<<dim3(DD / 128, MM / 128), 256, 0, stream>>>(attn_bf, Wob, bo, out, MM, DD, DD);
}